// Round 21
// baseline (199.092 us; speedup 1.0000x reference)
//
#include <hip/hip_runtime.h>
#include <hip/hip_cooperative_groups.h>

namespace cg = cooperative_groups;

// GRNN (Nadaraya-Watson, Gaussian kernel) — fp8 MX-scaled MFMA, barrier-free
// full-K LDS. THIS ROUND: single cooperative kernel fusing prep + GEMM +
// reduce (2 grid.sync()) — removes ~2 launch gaps + the reduce node (~5us
// of the 28.7us total). 256 blocks x 512 thr, 1 block/CU (co-residency
// guaranteed for grid sync). Falls back to the proven 3-kernel R18 path if
// hipLaunchCooperativeKernel is rejected (e.g. by graph capture).
// X [4096,256], X_train [8192,256], y_train [8192,1] -> out [4096]

#define N_Q 4096
#define N_T 8192
#define DIM 256
#define QB 256
#define TB 256
#define NC (N_T / TB)             // 32 partial slices
#define NXB (N_T / TB)            // 32
#define NYB (N_Q / QB)            // 16
#define ROW_B 256                 // bytes per fp8 row (full K)
#define MAT_B (256 * ROW_B)       // 64 KB per 256-row matrix panel
#define K1f (-18.033688011112042f)   // -12.5 * log2(e)
#define K2f ( 36.067376022224084f)   //  25.0 * log2(e)

typedef __attribute__((ext_vector_type(4))) float f32x4;
typedef __attribute__((ext_vector_type(8))) int   i32x8;

__device__ __forceinline__ void gload16(const void* g, void* l) {
    __builtin_amdgcn_global_load_lds(
        (const __attribute__((address_space(1))) unsigned*)g,
        (__attribute__((address_space(3))) unsigned*)l, 16, 0, 0);
}

// fp32 -> fp8 e4m3fn (truncating). Layout [s:1][e:4][m:3] -> s|(e<<3)|m.
__device__ __forceinline__ unsigned f8cvt(float f) {
    unsigned u = __builtin_bit_cast(unsigned, f);
    int e = (int)((u >> 23) & 0xFF) - 120;   // e4m3 biased exponent (bias 7)
    unsigned m = (u >> 20) & 7;
    unsigned s = (u >> 24) & 0x80;
    if (e <= 0) return s;                    // flush small to 0
    if (e > 15) { e = 15; m = 6; }           // clamp to 448 (15,7 is NaN)
    return s | ((unsigned)e << 3) | m;
}

__device__ __forceinline__ i32x8 ld_frag(const char* p) {
    int4 lo = *(const int4*)p;
    int4 hi = *(const int4*)(p + 16);
    i32x8 r;
    r[0] = lo.x; r[1] = lo.y; r[2] = lo.z; r[3] = lo.w;
    r[4] = hi.x; r[5] = hi.y; r[6] = hi.z; r[7] = hi.w;
    return r;
}

#define WVM0() asm volatile("s_waitcnt vmcnt(0)" ::: "memory")
#define WLG0() asm volatile("s_waitcnt lgkmcnt(0)" ::: "memory")
#define BARX() __builtin_amdgcn_s_barrier()
#define CFEN() asm volatile("" ::: "memory")

// one prep slot: convert 16 k-elems of one row to fp8 (16B store, swizzled),
// and accumulate the train-row norm across the 16-lane row group.
__device__ __forceinline__ void prep_slot(
    int row, int sub,
    const float* __restrict__ X, const float* __restrict__ XT,
    float* __restrict__ xt2s,
    unsigned char* __restrict__ Xb, unsigned char* __restrict__ XTb)
{
    const float* src; unsigned char* tdst; int r; bool train;
    if (row < N_Q) { r = row;       src = X  + (size_t)r * DIM; tdst = Xb;  train = false; }
    else           { r = row - N_Q; src = XT + (size_t)r * DIM; tdst = XTb; train = true; }

    const float4* s4 = (const float4*)(src + sub * 16);
    float4 v0 = s4[0], v1 = s4[1], v2 = s4[2], v3 = s4[3];

    unsigned w0 = f8cvt(v0.x) | (f8cvt(v0.y) << 8) | (f8cvt(v0.z) << 16) | (f8cvt(v0.w) << 24);
    unsigned w1 = f8cvt(v1.x) | (f8cvt(v1.y) << 8) | (f8cvt(v1.z) << 16) | (f8cvt(v1.w) << 24);
    unsigned w2 = f8cvt(v2.x) | (f8cvt(v2.y) << 8) | (f8cvt(v2.z) << 16) | (f8cvt(v2.w) << 24);
    unsigned w3 = f8cvt(v3.x) | (f8cvt(v3.y) << 8) | (f8cvt(v3.z) << 16) | (f8cvt(v3.w) << 24);

    int pair  = sub >> 1;
    int half  = sub & 1;
    int spair = pair ^ (r & 7);
    size_t byte = (size_t)r * ROW_B + (spair << 5) + half * 16;
    int4 w; w.x = (int)w0; w.y = (int)w1; w.z = (int)w2; w.w = (int)w3;
    *(int4*)(tdst + byte) = w;

    if (train) {
        float s = v0.x*v0.x + v0.y*v0.y + v0.z*v0.z + v0.w*v0.w
                + v1.x*v1.x + v1.y*v1.y + v1.z*v1.z + v1.w*v1.w
                + v2.x*v2.x + v2.y*v2.y + v2.z*v2.z + v2.w*v2.w
                + v3.x*v3.x + v3.y*v3.y + v3.z*v3.z + v3.w*v3.w;
        s += __shfl_xor(s, 1);
        s += __shfl_xor(s, 2);
        s += __shfl_xor(s, 4);
        s += __shfl_xor(s, 8);
        if (sub == 0) xt2s[r] = K1f * s;
    }
}

// ---- fused cooperative kernel: prep | grid.sync | GEMM | grid.sync | reduce
__global__ __launch_bounds__(512, 1) void grnn_fused(
    const float* __restrict__ X, const float* __restrict__ XT,
    const float* __restrict__ y, float* __restrict__ xt2s,
    unsigned char* __restrict__ Xb, unsigned char* __restrict__ XTb,
    float* __restrict__ pnum, float* __restrict__ pden,
    float* __restrict__ out)
{
    __shared__ char  lds[2][MAT_B];    // [A=query | B=train] = 128 KB
    __shared__ float comb[8 * 256];    // 8 KB

    const int bid = blockIdx.x;        // 0..255
    const int t   = threadIdx.x;

    // ---- phase 1: prep — 48 rows per block (768 slots over 512 threads) ---
    {
        int base = bid * 48;
        prep_slot(base + (t >> 4), t & 15, X, XT, xt2s, Xb, XTb);
        if (t < 256) {
            int s = t + 512;
            prep_slot(base + (s >> 4), s & 15, X, XT, xt2s, Xb, XTb);
        }
    }
    __threadfence();
    cg::this_grid().sync();

    // ---- phase 2: persistent 2-tile GEMM (R20 structure) -------------------
    const int xcd = bid & 7;
    const int idx = bid >> 3;            // 0..31
    const int bx  = xcd * 4 + (idx & 3); // 0..31
    const int by0 = idx >> 2;            // 0..7 ; tile2 = by0+8

    const int lane = t & 63;
    const int wid  = t >> 6;
    const int wm   = wid >> 2;
    const int wn   = wid & 3;
    const int tb   = bx * TB;
    const int fr   = lane & 15;
    const int fq   = lane >> 4;
    const int swz  = fr & 7;

    const char* gB  = (const char*)XTb + (size_t)bx * MAT_B;
    const char* gA0 = (const char*)Xb  + (size_t)by0 * MAT_B;
    const char* gA1 = (const char*)Xb  + (size_t)(by0 + 8) * MAT_B;

    int arow[8], brow[4];
    #pragma unroll
    for (int f = 0; f < 8; ++f) arow[f] = wm * 128 + f * 16 + fr;
    #pragma unroll
    for (int f = 0; f < 4; ++f) brow[f] = wn * 64 + f * 16 + fr;

    f32x4 acc[8][4];

    #define COMPUTE() do {                                                     \
        _Pragma("unroll")                                                      \
        for (int kt = 0; kt < 2; ++kt) {                                       \
            const int sp = ((kt * 4 + fq) ^ swz) << 5;                         \
            i32x8 bfrag[4];                                                    \
            _Pragma("unroll")                                                  \
            for (int nf = 0; nf < 4; ++nf)                                     \
                bfrag[nf] = ld_frag(&lds[1][brow[nf] * ROW_B + sp]);           \
            _Pragma("unroll")                                                  \
            for (int mf = 0; mf < 8; ++mf) {                                   \
                i32x8 afrag = ld_frag(&lds[0][arow[mf] * ROW_B + sp]);         \
                _Pragma("unroll")                                              \
                for (int nf = 0; nf < 4; ++nf)                                 \
                    acc[mf][nf] =                                              \
                        __builtin_amdgcn_mfma_scale_f32_16x16x128_f8f6f4(      \
                            bfrag[nf], afrag, acc[mf][nf],                     \
                            0, 0, 0, 0x7F7F7F7F, 0, 0x7F7F7F7F);               \
            }                                                                  \
        }                                                                      \
    } while (0)

    #define EPILOGUE(qb_) do {                                                 \
        float nv[8] = {}, dv[8] = {};                                          \
        _Pragma("unroll")                                                      \
        for (int nf = 0; nf < 4; ++nf)                                         \
            _Pragma("unroll")                                                  \
            for (int rr = 0; rr < 4; ++rr) {                                   \
                int n = tb + wn * 64 + nf * 16 + fq * 4 + rr;                  \
                float ts = xt2s[n];                                            \
                float yy = y[n];                                               \
                _Pragma("unroll")                                              \
                for (int mf = 0; mf < 8; ++mf) {                               \
                    float s = fmaf(K2f, acc[mf][nf][rr], ts);                  \
                    float w;                                                   \
                    asm("v_exp_f32 %0, %1" : "=v"(w) : "v"(s));                \
                    nv[mf] = fmaf(w, yy, nv[mf]);                              \
                    dv[mf] += w;                                               \
                }                                                              \
            }                                                                  \
        _Pragma("unroll")                                                      \
        for (int mf = 0; mf < 8; ++mf) {                                       \
            nv[mf] += __shfl_xor(nv[mf], 16);                                  \
            nv[mf] += __shfl_xor(nv[mf], 32);                                  \
            dv[mf] += __shfl_xor(dv[mf], 16);                                  \
            dv[mf] += __shfl_xor(dv[mf], 32);                                  \
        }                                                                      \
        if (fq == 0) {                                                         \
            _Pragma("unroll")                                                  \
            for (int mf = 0; mf < 8; ++mf) {                                   \
                int row = wm * 128 + mf * 16 + fr;                             \
                comb[(wn * 2 + 0) * 256 + row] = nv[mf];                       \
                comb[(wn * 2 + 1) * 256 + row] = dv[mf];                       \
            }                                                                  \
        }                                                                      \
        WLG0(); BARX();   /* raw barrier: no vmcnt drain (stage in flight) */  \
        {                                                                      \
            int row = t & 255;                                                 \
            int arr = t >> 8;                                                  \
            float s = comb[(0 * 2 + arr) * 256 + row]                          \
                    + comb[(1 * 2 + arr) * 256 + row]                          \
                    + comb[(2 * 2 + arr) * 256 + row]                          \
                    + comb[(3 * 2 + arr) * 256 + row];                         \
            float* dst = arr ? pden : pnum;                                    \
            dst[(size_t)((qb_) + row) * NC + bx] = s;                          \
        }                                                                      \
    } while (0)

    // tile 1: stage A(by0) + B, drain, compute
    #pragma unroll
    for (int i = 0; i < 8; ++i)
        gload16(gA0 + i * 8192 + t * 16, &lds[0][i * 8192 + t * 16]);
    #pragma unroll
    for (int i = 0; i < 8; ++i)
        gload16(gB + i * 8192 + t * 16, &lds[1][i * 8192 + t * 16]);
    WVM0(); BARX();

    #pragma unroll
    for (int mf = 0; mf < 8; ++mf)
        #pragma unroll
        for (int nf = 0; nf < 4; ++nf) acc[mf][nf] = (f32x4){0.f, 0.f, 0.f, 0.f};
    COMPUTE();
    CFEN(); BARX(); CFEN();              // all waves' lds[0] reads complete

    // issue tile-2 A-stage (flies under epilogue 1)
    #pragma unroll
    for (int i = 0; i < 8; ++i)
        gload16(gA1 + i * 8192 + t * 16, &lds[0][i * 8192 + t * 16]);
    CFEN();

    EPILOGUE(by0 * QB);

    WVM0(); BARX();                      // A(by0+8) landed (B untouched)

    #pragma unroll
    for (int mf = 0; mf < 8; ++mf)
        #pragma unroll
        for (int nf = 0; nf < 4; ++nf) acc[mf][nf] = (f32x4){0.f, 0.f, 0.f, 0.f};
    COMPUTE();
    CFEN(); BARX();

    EPILOGUE((by0 + 8) * QB);

    #undef COMPUTE
    #undef EPILOGUE

    // ---- phase 3: reduce — 16 rows per block --------------------------------
    __threadfence();
    cg::this_grid().sync();
    {
        int m   = bid * 16 + (t >> 5);   // 0..4095
        int l32 = t & 31;
        float n = pnum[(size_t)m * NC + l32];
        float d = pden[(size_t)m * NC + l32];
        #pragma unroll
        for (int off = 1; off < 32; off <<= 1) {
            n += __shfl_xor(n, off);
            d += __shfl_xor(d, off);
        }
        if (l32 == 0) out[m] = n / (d + 1e-9f);
    }
}

// ================== fallback path: the proven R18 trio ======================
__global__ __launch_bounds__(256) void grnn_prep(
    const float* __restrict__ X, const float* __restrict__ XT,
    float* __restrict__ xt2s,
    unsigned char* __restrict__ Xb, unsigned char* __restrict__ XTb)
{
    int wave = blockIdx.x * 4 + (threadIdx.x >> 6);
    int lane = threadIdx.x & 63;
    int row  = wave * 4 + (lane >> 4);
    prep_slot(row, lane & 15, X, XT, xt2s, Xb, XTb);
}

__global__ __launch_bounds__(512, 2) void grnn_mfma8(
    const unsigned char* __restrict__ Xb, const unsigned char* __restrict__ XTb,
    const float* __restrict__ y, const float* __restrict__ xt2s,
    float* __restrict__ pnum, float* __restrict__ pden)
{
    __shared__ char lds[2][MAT_B];   // 128 KB

    const int bid = blockIdx.x;
    const int xcd = bid & 7;
    const int idx = bid >> 3;            // 0..63
    const int bx  = xcd * 4 + (idx & 3); // 0..31
    const int by  = idx >> 2;            // 0..15

    const int t    = threadIdx.x;
    const int lane = t & 63;
    const int wid  = t >> 6;
    const int wm   = wid >> 2;
    const int wn   = wid & 3;
    const int qb   = by * QB;
    const int tb   = bx * TB;
    const int fr   = lane & 15;
    const int fq   = lane >> 4;
    const int swz  = fr & 7;

    const char* gA = (const char*)Xb  + (size_t)by * MAT_B;
    const char* gB = (const char*)XTb + (size_t)bx * MAT_B;

    int arow[8], brow[4];
    #pragma unroll
    for (int f = 0; f < 8; ++f) arow[f] = wm * 128 + f * 16 + fr;
    #pragma unroll
    for (int f = 0; f < 4; ++f) brow[f] = wn * 64 + f * 16 + fr;

    #pragma unroll
    for (int i = 0; i < 8; ++i)
        gload16(gA + i * 8192 + t * 16, &lds[0][i * 8192 + t * 16]);
    #pragma unroll
    for (int i = 0; i < 8; ++i)
        gload16(gB + i * 8192 + t * 16, &lds[1][i * 8192 + t * 16]);
    WVM0(); BARX();

    f32x4 acc[8][4] = {};
    #pragma unroll
    for (int kt = 0; kt < 2; ++kt) {
        const int sp = ((kt * 4 + fq) ^ swz) << 5;
        i32x8 bfrag[4];
        #pragma unroll
        for (int nf = 0; nf < 4; ++nf)
            bfrag[nf] = ld_frag(&lds[1][brow[nf] * ROW_B + sp]);
        #pragma unroll
        for (int mf = 0; mf < 8; ++mf) {
            i32x8 afrag = ld_frag(&lds[0][arow[mf] * ROW_B + sp]);
            #pragma unroll
            for (int nf = 0; nf < 4; ++nf)
                acc[mf][nf] = __builtin_amdgcn_mfma_scale_f32_16x16x128_f8f6f4(
                    bfrag[nf], afrag, acc[mf][nf],
                    0, 0, 0, 0x7F7F7F7F, 0, 0x7F7F7F7F);
        }
    }

    float nv[8] = {}, dv[8] = {};
    #pragma unroll
    for (int nf = 0; nf < 4; ++nf)
        #pragma unroll
        for (int rr = 0; rr < 4; ++rr) {
            int n = tb + wn * 64 + nf * 16 + fq * 4 + rr;
            float ts = xt2s[n];
            float yy = y[n];
            #pragma unroll
            for (int mf = 0; mf < 8; ++mf) {
                float s = fmaf(K2f, acc[mf][nf][rr], ts);
                float w;
                asm("v_exp_f32 %0, %1" : "=v"(w) : "v"(s));
                nv[mf] = fmaf(w, yy, nv[mf]);
                dv[mf] += w;
            }
        }

    #pragma unroll
    for (int mf = 0; mf < 8; ++mf) {
        nv[mf] += __shfl_xor(nv[mf], 16);
        nv[mf] += __shfl_xor(nv[mf], 32);
        dv[mf] += __shfl_xor(dv[mf], 16);
        dv[mf] += __shfl_xor(dv[mf], 32);
    }

    float* comb = (float*)&lds[0][0];
    __syncthreads();
    if (fq == 0) {
        #pragma unroll
        for (int mf = 0; mf < 8; ++mf) {
            int row = wm * 128 + mf * 16 + fr;
            comb[(wn * 2 + 0) * 256 + row] = nv[mf];
            comb[(wn * 2 + 1) * 256 + row] = dv[mf];
        }
    }
    __syncthreads();
    {
        int row = t & 255;
        int arr = t >> 8;
        float s = comb[(0 * 2 + arr) * 256 + row] + comb[(1 * 2 + arr) * 256 + row]
                + comb[(2 * 2 + arr) * 256 + row] + comb[(3 * 2 + arr) * 256 + row];
        float* dst = arr ? pden : pnum;
        dst[(size_t)(qb + row) * NC + bx] = s;
    }
}

__global__ __launch_bounds__(256) void grnn_reduce(const float* __restrict__ pnum,
                                                   const float* __restrict__ pden,
                                                   float* __restrict__ out) {
    int wv   = blockIdx.x * 4 + (threadIdx.x >> 6);
    int lane = threadIdx.x & 63;
    float n = 0.f, d = 0.f;
    if (lane < NC) {
        n = pnum[(size_t)wv * NC + lane];
        d = pden[(size_t)wv * NC + lane];
    }
    #pragma unroll
    for (int off = 1; off < 64; off <<= 1) {
        n += __shfl_xor(n, off);
        d += __shfl_xor(d, off);
    }
    if (lane == 0) out[wv] = n / (d + 1e-9f);
}

// ---- launch -----------------------------------------------------------------
extern "C" void kernel_launch(void* const* d_in, const int* in_sizes, int n_in,
                              void* d_out, int out_size, void* d_ws, size_t ws_size,
                              hipStream_t stream) {
    const float* X  = (const float*)d_in[0];
    const float* XT = (const float*)d_in[1];
    const float* y  = (const float*)d_in[2];
    float* out = (float*)d_out;
    char*  ws  = (char*)d_ws;

    const size_t off_pnum = 0;                                  // 512 KB
    const size_t off_pden = off_pnum + (size_t)N_Q * NC * 4;    // 512 KB
    const size_t off_xt2  = off_pden + (size_t)N_Q * NC * 4;    // 32 KB
    const size_t off_Xb   = off_xt2  + (size_t)N_T * 4;         // 1 MB fp8
    const size_t off_XTb  = off_Xb   + (size_t)N_Q * DIM;       // 2 MB fp8
    const size_t need     = off_XTb  + (size_t)N_T * DIM;       // ~4.03 MB

    float* pnum = (float*)(ws + off_pnum);
    float* pden = (float*)(ws + off_pden);
    float* xt2s = (float*)(ws + off_xt2);
    unsigned char* Xb  = (unsigned char*)(ws + off_Xb);
    unsigned char* XTb = (unsigned char*)(ws + off_XTb);

    (void)in_sizes; (void)n_in; (void)out_size; (void)ws_size; (void)need;

    // try the fused cooperative kernel first
    const float* Xp = X; const float* XTp = XT; const float* yp = y;
    float* xt2sp = xt2s; unsigned char* Xbp = Xb; unsigned char* XTbp = XTb;
    float* pnump = pnum; float* pdenp = pden; float* outp = out;
    void* args[9] = {
        (void*)&Xp, (void*)&XTp, (void*)&yp, (void*)&xt2sp,
        (void*)&Xbp, (void*)&XTbp, (void*)&pnump, (void*)&pdenp, (void*)&outp
    };
    hipError_t err = hipLaunchCooperativeKernel(
        (const void*)grnn_fused, dim3(256), dim3(512), args, 0, stream);

    if (err != hipSuccess) {
        (void)hipGetLastError();   // clear sticky error, use the proven trio
        hipLaunchKernelGGL(grnn_prep, dim3((N_Q + N_T) / 16), dim3(256), 0, stream,
                           X, XT, xt2s, Xb, XTb);
        hipLaunchKernelGGL(grnn_mfma8, dim3(NXB * NYB), dim3(512), 0, stream,
                           Xb, XTb, y, xt2s, pnum, pden);
        hipLaunchKernelGGL(grnn_reduce, dim3(N_Q / 4), dim3(256), 0, stream,
                           pnum, pden, out);
    }
}

// Round 22
// 180.155 us; speedup vs baseline: 1.1051x; 1.1051x over previous
//
#include <hip/hip_runtime.h>

// GRNN (Nadaraya-Watson, Gaussian kernel) — fp8 MX-scaled MFMA, barrier-free
// full-K LDS (R18 structure, best 28.7us). THIS ROUND: fused atomic-ticket
// tail reduce — every block bumps a device counter after its partials are
// globally visible; the LAST 64 blocks (tickets >= 448) spin until all 512
// have finished, then each reduces 64 output rows into d_out. Removes the
// reduce kernel + one launch gap without cooperative-launch machinery
// (R21: cg::grid().sync() cost ~75us+ per sync — rejected).
// Deadlock-free: spinners only exist once 448 blocks finished; <=64 unfinished
// + <=64 spinners <= 256 CUs at 1 block/CU. Counter zeroed by prep each call.
// X [4096,256], X_train [8192,256], y_train [8192,1] -> out [4096]

#define N_Q 4096
#define N_T 8192
#define DIM 256
#define QB 256
#define TB 256
#define NC (N_T / TB)             // 32 partial slices
#define NXB (N_T / TB)            // 32
#define NYB (N_Q / QB)            // 16
#define NBLK (NXB * NYB)          // 512 main blocks
#define NRED 64                   // reducer blocks (tickets >= NBLK-NRED)
#define ROW_B 256                 // bytes per fp8 row (full K)
#define MAT_B (256 * ROW_B)       // 64 KB per 256-row matrix panel
#define K1f (-18.033688011112042f)   // -12.5 * log2(e)
#define K2f ( 36.067376022224084f)   //  25.0 * log2(e)

typedef __attribute__((ext_vector_type(4))) float f32x4;
typedef __attribute__((ext_vector_type(8))) int   i32x8;

__device__ __forceinline__ void gload16(const void* g, void* l) {
    __builtin_amdgcn_global_load_lds(
        (const __attribute__((address_space(1))) unsigned*)g,
        (__attribute__((address_space(3))) unsigned*)l, 16, 0, 0);
}

// fp32 -> fp8 e4m3fn (truncating). Layout [s:1][e:4][m:3] -> s|(e<<3)|m.
__device__ __forceinline__ unsigned f8cvt(float f) {
    unsigned u = __builtin_bit_cast(unsigned, f);
    int e = (int)((u >> 23) & 0xFF) - 120;   // e4m3 biased exponent (bias 7)
    unsigned m = (u >> 20) & 7;
    unsigned s = (u >> 24) & 0x80;
    if (e <= 0) return s;                    // flush small to 0
    if (e > 15) { e = 15; m = 6; }           // clamp to 448 (15,7 is NaN)
    return s | ((unsigned)e << 3) | m;
}

__device__ __forceinline__ i32x8 ld_frag(const char* p) {
    int4 lo = *(const int4*)p;
    int4 hi = *(const int4*)(p + 16);
    i32x8 r;
    r[0] = lo.x; r[1] = lo.y; r[2] = lo.z; r[3] = lo.w;
    r[4] = hi.x; r[5] = hi.y; r[6] = hi.z; r[7] = hi.w;
    return r;
}

#define WVM0() asm volatile("s_waitcnt vmcnt(0)" ::: "memory")
#define BARX() __builtin_amdgcn_s_barrier()

// ---- prep: 4 rows/wave, 16 lanes/row, 16B stores + counter zero ------------
__global__ __launch_bounds__(256) void grnn_prep(
    const float* __restrict__ X, const float* __restrict__ XT,
    float* __restrict__ xt2s,
    unsigned char* __restrict__ Xb, unsigned char* __restrict__ XTb,
    int* __restrict__ cnt)
{
    if (blockIdx.x == 0 && threadIdx.x == 0) *cnt = 0;   // visible to next kernel

    int wave = blockIdx.x * 4 + (threadIdx.x >> 6);
    int lane = threadIdx.x & 63;
    int row  = wave * 4 + (lane >> 4);
    int sub  = lane & 15;
    const float* src; unsigned char* tdst; int r; bool train;
    if (row < N_Q) { r = row;       src = X  + (size_t)r * DIM; tdst = Xb;  train = false; }
    else           { r = row - N_Q; src = XT + (size_t)r * DIM; tdst = XTb; train = true; }

    const float4* s4 = (const float4*)(src + sub * 16);
    float4 v0 = s4[0], v1 = s4[1], v2 = s4[2], v3 = s4[3];

    unsigned w0 = f8cvt(v0.x) | (f8cvt(v0.y) << 8) | (f8cvt(v0.z) << 16) | (f8cvt(v0.w) << 24);
    unsigned w1 = f8cvt(v1.x) | (f8cvt(v1.y) << 8) | (f8cvt(v1.z) << 16) | (f8cvt(v1.w) << 24);
    unsigned w2 = f8cvt(v2.x) | (f8cvt(v2.y) << 8) | (f8cvt(v2.z) << 16) | (f8cvt(v2.w) << 24);
    unsigned w3 = f8cvt(v3.x) | (f8cvt(v3.y) << 8) | (f8cvt(v3.z) << 16) | (f8cvt(v3.w) << 24);

    int pair  = sub >> 1;
    int half  = sub & 1;
    int spair = pair ^ (r & 7);
    size_t byte = (size_t)r * ROW_B + (spair << 5) + half * 16;
    int4 w; w.x = (int)w0; w.y = (int)w1; w.z = (int)w2; w.w = (int)w3;
    *(int4*)(tdst + byte) = w;

    if (train) {
        float s = v0.x*v0.x + v0.y*v0.y + v0.z*v0.z + v0.w*v0.w
                + v1.x*v1.x + v1.y*v1.y + v1.z*v1.z + v1.w*v1.w
                + v2.x*v2.x + v2.y*v2.y + v2.z*v2.z + v2.w*v2.w
                + v3.x*v3.x + v3.y*v3.y + v3.z*v3.z + v3.w*v3.w;
        s += __shfl_xor(s, 1);
        s += __shfl_xor(s, 2);
        s += __shfl_xor(s, 4);
        s += __shfl_xor(s, 8);
        if (sub == 0) xt2s[r] = K1f * s;
    }
}

// ---- main: 256x256 tile, full-K LDS, MX MFMA, fused ticket-tail reduce -----
__global__ __launch_bounds__(512, 1) void grnn_mfma11(
    const unsigned char* __restrict__ Xb, const unsigned char* __restrict__ XTb,
    const float* __restrict__ y, const float* __restrict__ xt2s,
    float* __restrict__ pnum, float* __restrict__ pden,
    float* __restrict__ out, int* __restrict__ cnt)
{
    __shared__ char lds[2][MAT_B];   // [A=query | B=train] = 128 KB
    __shared__ int  tk;

    const int bid = blockIdx.x;
    const int xcd = bid & 7;
    const int idx = bid >> 3;            // 0..63
    const int bx  = xcd * 4 + (idx & 3); // 0..31
    const int by  = idx >> 2;            // 0..15

    const int t    = threadIdx.x;
    const int lane = t & 63;
    const int wid  = t >> 6;             // 0..7
    const int wm   = wid >> 2;           // 0..1
    const int wn   = wid & 3;            // 0..3
    const int qb   = by * QB;
    const int tb   = bx * TB;
    const int fr   = lane & 15;
    const int fq   = lane >> 4;
    const int swz  = fr & 7;

    const char* gA = (const char*)Xb  + (size_t)by * MAT_B;
    const char* gB = (const char*)XTb + (size_t)bx * MAT_B;

    int arow[8], brow[4];
    #pragma unroll
    for (int f = 0; f < 8; ++f) arow[f] = wm * 128 + f * 16 + fr;
    #pragma unroll
    for (int f = 0; f < 4; ++f) brow[f] = wn * 64 + f * 16 + fr;

    // ---- stage everything, single drain ------------------------------------
    #pragma unroll
    for (int i = 0; i < 8; ++i)
        gload16(gA + i * 8192 + t * 16, &lds[0][i * 8192 + t * 16]);
    #pragma unroll
    for (int i = 0; i < 8; ++i)
        gload16(gB + i * 8192 + t * 16, &lds[1][i * 8192 + t * 16]);
    WVM0(); BARX();

    // ---- barrier-free compute: 64 MX MFMA (K=128 each) ---------------------
    f32x4 acc[8][4] = {};
    #pragma unroll
    for (int kt = 0; kt < 2; ++kt) {
        const int sp = ((kt * 4 + fq) ^ swz) << 5;
        i32x8 bfrag[4];
        #pragma unroll
        for (int nf = 0; nf < 4; ++nf)
            bfrag[nf] = ld_frag(&lds[1][brow[nf] * ROW_B + sp]);
        #pragma unroll
        for (int mf = 0; mf < 8; ++mf) {
            i32x8 afrag = ld_frag(&lds[0][arow[mf] * ROW_B + sp]);
            #pragma unroll
            for (int nf = 0; nf < 4; ++nf)
                acc[mf][nf] = __builtin_amdgcn_mfma_scale_f32_16x16x128_f8f6f4(
                    bfrag[nf], afrag, acc[mf][nf],
                    0, 0, 0, 0x7F7F7F7F, 0, 0x7F7F7F7F);
        }
    }

    // ---- epilogue: w' = exp2(K2*c + xt2s[n]); in-lane n-reduce -------------
    float nv[8] = {}, dv[8] = {};
    #pragma unroll
    for (int nf = 0; nf < 4; ++nf)
        #pragma unroll
        for (int rr = 0; rr < 4; ++rr) {
            int n = tb + wn * 64 + nf * 16 + fq * 4 + rr;
            float ts = xt2s[n];
            float yy = y[n];
            #pragma unroll
            for (int mf = 0; mf < 8; ++mf) {
                float s = fmaf(K2f, acc[mf][nf][rr], ts);
                float w;
                asm("v_exp_f32 %0, %1" : "=v"(w) : "v"(s));  // 2^s, ->0 underflow
                nv[mf] = fmaf(w, yy, nv[mf]);
                dv[mf] += w;
            }
        }

    #pragma unroll
    for (int mf = 0; mf < 8; ++mf) {
        nv[mf] += __shfl_xor(nv[mf], 16);
        nv[mf] += __shfl_xor(nv[mf], 32);
        dv[mf] += __shfl_xor(dv[mf], 16);
        dv[mf] += __shfl_xor(dv[mf], 32);
    }

    // cross-wn combine (overlay lds[0]) -> pnum/pden slice [m][NC]
    float* comb = (float*)&lds[0][0];
    __syncthreads();
    if (fq == 0) {
        #pragma unroll
        for (int mf = 0; mf < 8; ++mf) {
            int row = wm * 128 + mf * 16 + fr;
            comb[(wn * 2 + 0) * 256 + row] = nv[mf];
            comb[(wn * 2 + 1) * 256 + row] = dv[mf];
        }
    }
    __syncthreads();
    {
        int row = t & 255;
        int arr = t >> 8;
        float s = comb[(0 * 2 + arr) * 256 + row] + comb[(1 * 2 + arr) * 256 + row]
                + comb[(2 * 2 + arr) * 256 + row] + comb[(3 * 2 + arr) * 256 + row];
        float* dst = arr ? pden : pnum;
        dst[(size_t)(qb + row) * NC + bx] = s;
    }

    // ---- fused tail: ticket; last NRED blocks reduce into out --------------
    __threadfence();                 // partials globally visible before ticket
    __syncthreads();
    if (t == 0) tk = atomicAdd(cnt, 1);
    __syncthreads();
    int ticket = tk;
    if (ticket < NBLK - NRED) return;

    if (t == 0) {                    // wait for ALL partials
        while (atomicAdd(cnt, 0) < NBLK) __builtin_amdgcn_s_sleep(2);
    }
    __syncthreads();
    __threadfence();                 // acquire: invalidate stale cached lines

    int rid = ticket - (NBLK - NRED);         // 0..63 -> rows [rid*64, +64)
    #pragma unroll
    for (int p = 0; p < 4; ++p) {
        int m   = rid * 64 + p * 16 + (t >> 5);   // 16 rows per pass
        int l32 = t & 31;
        float n = pnum[(size_t)m * NC + l32];
        float d = pden[(size_t)m * NC + l32];
        #pragma unroll
        for (int off = 1; off < 32; off <<= 1) {
            n += __shfl_xor(n, off);
            d += __shfl_xor(d, off);
        }
        if (l32 == 0) out[m] = n / (d + 1e-9f);
    }
}

// ---- launch -----------------------------------------------------------------
extern "C" void kernel_launch(void* const* d_in, const int* in_sizes, int n_in,
                              void* d_out, int out_size, void* d_ws, size_t ws_size,
                              hipStream_t stream) {
    const float* X  = (const float*)d_in[0];
    const float* XT = (const float*)d_in[1];
    const float* y  = (const float*)d_in[2];
    float* out = (float*)d_out;
    char*  ws  = (char*)d_ws;

    const size_t off_pnum = 0;                                  // 512 KB
    const size_t off_pden = off_pnum + (size_t)N_Q * NC * 4;    // 512 KB
    const size_t off_xt2  = off_pden + (size_t)N_Q * NC * 4;    // 32 KB
    const size_t off_Xb   = off_xt2  + (size_t)N_T * 4;         // 1 MB fp8
    const size_t off_XTb  = off_Xb   + (size_t)N_Q * DIM;       // 2 MB fp8
    const size_t off_cnt  = off_XTb  + (size_t)N_T * DIM;       // 4 B counter

    float* pnum = (float*)(ws + off_pnum);
    float* pden = (float*)(ws + off_pden);
    float* xt2s = (float*)(ws + off_xt2);
    unsigned char* Xb  = (unsigned char*)(ws + off_Xb);
    unsigned char* XTb = (unsigned char*)(ws + off_XTb);
    int*   cnt  = (int*)(ws + off_cnt);

    (void)in_sizes; (void)n_in; (void)out_size; (void)ws_size;

    hipLaunchKernelGGL(grnn_prep, dim3((N_Q + N_T) / 16), dim3(256), 0, stream,
                       X, XT, xt2s, Xb, XTb, cnt);
    hipLaunchKernelGGL(grnn_mfma11, dim3(NBLK), dim3(512), 0, stream,
                       Xb, XTb, y, xt2s, pnum, pden, out, cnt);
}

// Round 23
// 28.479 us; speedup vs baseline: 6.9908x; 6.3259x over previous
//
#include <hip/hip_runtime.h>

// GRNN (Nadaraya-Watson, Gaussian kernel) — fp8 MX-scaled MFMA, barrier-free
// full-K LDS (R18 structure, best 28.7us). R21/R22 post-mortem: same-kernel
// cross-block reduce via grid.sync or threadfence+ticket costs ~150us on
// gfx950 (device-scope fences = L2 writeback-invalidate) — kernel launch
// boundaries ARE the cheap grid barrier. This round: exact R18 revert +
// reduce kernel uses all 64 lanes (2 rows/wave via 32-lane groups).
// X [4096,256], X_train [8192,256], y_train [8192,1] -> out [4096]

#define N_Q 4096
#define N_T 8192
#define DIM 256
#define QB 256
#define TB 256
#define NC (N_T / TB)             // 32 partial slices
#define NXB (N_T / TB)            // 32
#define NYB (N_Q / QB)            // 16
#define ROW_B 256                 // bytes per fp8 row (full K)
#define MAT_B (256 * ROW_B)       // 64 KB per 256-row matrix panel
#define K1f (-18.033688011112042f)   // -12.5 * log2(e)
#define K2f ( 36.067376022224084f)   //  25.0 * log2(e)

typedef __attribute__((ext_vector_type(4))) float f32x4;
typedef __attribute__((ext_vector_type(8))) int   i32x8;

__device__ __forceinline__ void gload16(const void* g, void* l) {
    __builtin_amdgcn_global_load_lds(
        (const __attribute__((address_space(1))) unsigned*)g,
        (__attribute__((address_space(3))) unsigned*)l, 16, 0, 0);
}

// fp32 -> fp8 e4m3fn (truncating). Layout [s:1][e:4][m:3] -> s|(e<<3)|m.
__device__ __forceinline__ unsigned f8cvt(float f) {
    unsigned u = __builtin_bit_cast(unsigned, f);
    int e = (int)((u >> 23) & 0xFF) - 120;   // e4m3 biased exponent (bias 7)
    unsigned m = (u >> 20) & 7;
    unsigned s = (u >> 24) & 0x80;
    if (e <= 0) return s;                    // flush small to 0
    if (e > 15) { e = 15; m = 6; }           // clamp to 448 (15,7 is NaN)
    return s | ((unsigned)e << 3) | m;
}

__device__ __forceinline__ i32x8 ld_frag(const char* p) {
    int4 lo = *(const int4*)p;
    int4 hi = *(const int4*)(p + 16);
    i32x8 r;
    r[0] = lo.x; r[1] = lo.y; r[2] = lo.z; r[3] = lo.w;
    r[4] = hi.x; r[5] = hi.y; r[6] = hi.z; r[7] = hi.w;
    return r;
}

#define WVM0() asm volatile("s_waitcnt vmcnt(0)" ::: "memory")
#define BARX() __builtin_amdgcn_s_barrier()

// ---- prep: 4 rows/wave, 16 lanes/row, 16B stores (R18, unchanged) ----------
__global__ __launch_bounds__(256) void grnn_prep(
    const float* __restrict__ X, const float* __restrict__ XT,
    float* __restrict__ xt2s,
    unsigned char* __restrict__ Xb, unsigned char* __restrict__ XTb)
{
    int wave = blockIdx.x * 4 + (threadIdx.x >> 6);
    int lane = threadIdx.x & 63;
    int row  = wave * 4 + (lane >> 4);
    int sub  = lane & 15;
    const float* src; unsigned char* tdst; int r; bool train;
    if (row < N_Q) { r = row;       src = X  + (size_t)r * DIM; tdst = Xb;  train = false; }
    else           { r = row - N_Q; src = XT + (size_t)r * DIM; tdst = XTb; train = true; }

    const float4* s4 = (const float4*)(src + sub * 16);
    float4 v0 = s4[0], v1 = s4[1], v2 = s4[2], v3 = s4[3];

    unsigned w0 = f8cvt(v0.x) | (f8cvt(v0.y) << 8) | (f8cvt(v0.z) << 16) | (f8cvt(v0.w) << 24);
    unsigned w1 = f8cvt(v1.x) | (f8cvt(v1.y) << 8) | (f8cvt(v1.z) << 16) | (f8cvt(v1.w) << 24);
    unsigned w2 = f8cvt(v2.x) | (f8cvt(v2.y) << 8) | (f8cvt(v2.z) << 16) | (f8cvt(v2.w) << 24);
    unsigned w3 = f8cvt(v3.x) | (f8cvt(v3.y) << 8) | (f8cvt(v3.z) << 16) | (f8cvt(v3.w) << 24);

    int pair  = sub >> 1;
    int half  = sub & 1;
    int spair = pair ^ (r & 7);
    size_t byte = (size_t)r * ROW_B + (spair << 5) + half * 16;
    int4 w; w.x = (int)w0; w.y = (int)w1; w.z = (int)w2; w.w = (int)w3;
    *(int4*)(tdst + byte) = w;

    if (train) {
        float s = v0.x*v0.x + v0.y*v0.y + v0.z*v0.z + v0.w*v0.w
                + v1.x*v1.x + v1.y*v1.y + v1.z*v1.z + v1.w*v1.w
                + v2.x*v2.x + v2.y*v2.y + v2.z*v2.z + v2.w*v2.w
                + v3.x*v3.x + v3.y*v3.y + v3.z*v3.z + v3.w*v3.w;
        s += __shfl_xor(s, 1);
        s += __shfl_xor(s, 2);
        s += __shfl_xor(s, 4);
        s += __shfl_xor(s, 8);
        if (sub == 0) xt2s[r] = K1f * s;
    }
}

// ---- main: 256x256 tile, 8 waves, full-K LDS, barrier-free MX-MFMA ---------
__global__ __launch_bounds__(512, 2) void grnn_mfma8(
    const unsigned char* __restrict__ Xb, const unsigned char* __restrict__ XTb,
    const float* __restrict__ y, const float* __restrict__ xt2s,
    float* __restrict__ pnum, float* __restrict__ pden)
{
    __shared__ char lds[2][MAT_B];   // [A=query | B=train] = 128 KB

    // bijective XCD-chunked swizzle (512 = 8 XCD * 4 bx * 16 by)
    const int bid = blockIdx.x;
    const int xcd = bid & 7;
    const int idx = bid >> 3;            // 0..63
    const int bx  = xcd * 4 + (idx & 3); // 0..31
    const int by  = idx >> 2;            // 0..15

    const int t    = threadIdx.x;
    const int lane = t & 63;
    const int wid  = t >> 6;             // 0..7
    const int wm   = wid >> 2;           // 0..1  (m half: 128 query rows)
    const int wn   = wid & 3;            // 0..3  (n quarter: 64 train rows)
    const int qb   = by * QB;
    const int tb   = bx * TB;
    const int fr   = lane & 15;
    const int fq   = lane >> 4;          // k-group 0..3 (32 k-bytes each)
    const int swz  = fr & 7;             // row&7 for every frag row

    const char* gA = (const char*)Xb  + (size_t)by * MAT_B;
    const char* gB = (const char*)XTb + (size_t)bx * MAT_B;

    int arow[8], brow[4];
    #pragma unroll
    for (int f = 0; f < 8; ++f) arow[f] = wm * 128 + f * 16 + fr;
    #pragma unroll
    for (int f = 0; f < 4; ++f) brow[f] = wn * 64 + f * 16 + fr;

    // ---- stage EVERYTHING: 64 KB per matrix, 8 gload16/thread each --------
    #pragma unroll
    for (int i = 0; i < 8; ++i)
        gload16(gA + i * 8192 + t * 16, &lds[0][i * 8192 + t * 16]);
    #pragma unroll
    for (int i = 0; i < 8; ++i)
        gload16(gB + i * 8192 + t * 16, &lds[1][i * 8192 + t * 16]);
    WVM0(); BARX();                      // the ONLY K-path barrier

    // ---- barrier-free compute: 64 MX MFMA (K=128 each) --------------------
    f32x4 acc[8][4] = {};   // acc[mf][nf]: D rows = train n, cols = query m
    #pragma unroll
    for (int kt = 0; kt < 2; ++kt) {
        const int sp = ((kt * 4 + fq) ^ swz) << 5;   // swizzled 32B pair offset
        i32x8 bfrag[4];
        #pragma unroll
        for (int nf = 0; nf < 4; ++nf)
            bfrag[nf] = ld_frag(&lds[1][brow[nf] * ROW_B + sp]);
        #pragma unroll
        for (int mf = 0; mf < 8; ++mf) {
            i32x8 afrag = ld_frag(&lds[0][arow[mf] * ROW_B + sp]);
            #pragma unroll
            for (int nf = 0; nf < 4; ++nf)
                acc[mf][nf] = __builtin_amdgcn_mfma_scale_f32_16x16x128_f8f6f4(
                    bfrag[nf], afrag, acc[mf][nf],
                    0, 0,                        // cbsz=fp8, blgp=fp8
                    0, 0x7F7F7F7F,               // opsel_a, scale_a = 1.0
                    0, 0x7F7F7F7F);              // opsel_b, scale_b = 1.0
        }
    }

    // ---- epilogue: w' = exp2(K2*c + xt2s[n]); in-lane n-reduce -------------
    float nv[8] = {}, dv[8] = {};
    #pragma unroll
    for (int nf = 0; nf < 4; ++nf)
        #pragma unroll
        for (int rr = 0; rr < 4; ++rr) {
            int n = tb + wn * 64 + nf * 16 + fq * 4 + rr;
            float ts = xt2s[n];
            float yy = y[n];
            #pragma unroll
            for (int mf = 0; mf < 8; ++mf) {
                float s = fmaf(K2f, acc[mf][nf][rr], ts);
                float w;
                asm("v_exp_f32 %0, %1" : "=v"(w) : "v"(s));  // 2^s, ->0 underflow
                nv[mf] = fmaf(w, yy, nv[mf]);
                dv[mf] += w;
            }
        }

    #pragma unroll
    for (int mf = 0; mf < 8; ++mf) {
        nv[mf] += __shfl_xor(nv[mf], 16);
        nv[mf] += __shfl_xor(nv[mf], 32);
        dv[mf] += __shfl_xor(dv[mf], 16);
        dv[mf] += __shfl_xor(dv[mf], 32);
    }

    // Cross-wn combine in LDS (overlay; K-loop reads all done after barrier),
    // then one slice per block: pnum/pden layout [m][NC].
    float* comb = (float*)&lds[0][0];   // [wn][arr][256 rows] = 8 KB
    __syncthreads();                     // all waves done reading lds
    if (fq == 0) {
        #pragma unroll
        for (int mf = 0; mf < 8; ++mf) {
            int row = wm * 128 + mf * 16 + fr;
            comb[(wn * 2 + 0) * 256 + row] = nv[mf];
            comb[(wn * 2 + 1) * 256 + row] = dv[mf];
        }
    }
    __syncthreads();
    {
        int row = t & 255;
        int arr = t >> 8;                  // 0..1 (512 threads)
        float s = comb[(0 * 2 + arr) * 256 + row] + comb[(1 * 2 + arr) * 256 + row]
                + comb[(2 * 2 + arr) * 256 + row] + comb[(3 * 2 + arr) * 256 + row];
        float* dst = arr ? pden : pnum;
        dst[(size_t)(qb + row) * NC + bx] = s;
    }
}

// ---- reduce: 2 rows per wave (32-lane groups), all 64 lanes active ---------
__global__ __launch_bounds__(256) void grnn_reduce(const float* __restrict__ pnum,
                                                   const float* __restrict__ pden,
                                                   float* __restrict__ out) {
    int m   = blockIdx.x * 8 + (threadIdx.x >> 5);   // 0..4095
    int l32 = threadIdx.x & 31;                      // NC = 32
    float n = pnum[(size_t)m * NC + l32];
    float d = pden[(size_t)m * NC + l32];
    #pragma unroll
    for (int off = 1; off < 32; off <<= 1) {
        n += __shfl_xor(n, off);
        d += __shfl_xor(d, off);
    }
    if (l32 == 0) out[m] = n / (d + 1e-9f);
}

// ---- fallback path (fp32 atomics; only if ws is tiny) ----------------------
typedef __attribute__((ext_vector_type(8))) short bf16x8;

__global__ void grnn_zero(float* __restrict__ ws) {
    int i = blockIdx.x * 256 + threadIdx.x;
    if (i < 2 * N_Q) ws[i] = 0.0f;
}

__global__ __launch_bounds__(256) void grnn_rowsq(const float* __restrict__ X,
                                                  const float* __restrict__ XT,
                                                  float* __restrict__ xq2,
                                                  float* __restrict__ xt2) {
    int wave = blockIdx.x * 4 + (threadIdx.x >> 6);
    int lane = threadIdx.x & 63;
    if (wave >= N_Q + N_T) return;
    const float* src; float* dst;
    if (wave < N_Q) { src = X + (size_t)wave * DIM;          dst = xq2 + wave; }
    else            { src = XT + (size_t)(wave - N_Q) * DIM; dst = xt2 + (wave - N_Q); }
    float4 v = ((const float4*)src)[lane];
    float s = v.x*v.x + v.y*v.y + v.z*v.z + v.w*v.w;
    #pragma unroll
    for (int off = 32; off > 0; off >>= 1) s += __shfl_xor(s, off);
    if (lane == 0) *dst = s;
}

__device__ __forceinline__ unsigned pk_bf16(float lo, float hi) {
    unsigned a = __builtin_bit_cast(unsigned, lo);
    unsigned b = __builtin_bit_cast(unsigned, hi);
    return (b & 0xFFFF0000u) | (a >> 16);
}

__global__ __launch_bounds__(256, 2) void grnn_mfma_atomic(
    const float* __restrict__ X, const float* __restrict__ XT,
    const float* __restrict__ y, const float* __restrict__ xq2,
    const float* __restrict__ xt2,
    float* __restrict__ num, float* __restrict__ den)
{
    __shared__ char lds[2][2][16384];
    const int t = threadIdx.x, lane = t & 63, wid = t >> 6;
    const int wm = wid >> 1, wn = wid & 1;
    const int qb = blockIdx.y * 128, tb = blockIdx.x * 128;
    const int srow = t >> 3, sslot = t & 7, sswz = sslot ^ (srow & 7);
    const float* Ag = X  + (size_t)(qb + srow) * DIM + sslot * 8;
    const float* Bg = XT + (size_t)(tb + srow) * DIM + sslot * 8;
    float4 ra[4][2], rb[4][2];

    #define LOADT(kt)                                                          \
        _Pragma("unroll")                                                      \
        for (int p = 0; p < 4; ++p) {                                          \
            const float* ga = Ag + (size_t)(p * 32) * DIM + (kt) * 64;         \
            const float* gb = Bg + (size_t)(p * 32) * DIM + (kt) * 64;         \
            ra[p][0] = *(const float4*)ga;  ra[p][1] = *(const float4*)(ga+4); \
            rb[p][0] = *(const float4*)gb;  rb[p][1] = *(const float4*)(gb+4); \
        }
    #define WRITET(buf)                                                        \
        _Pragma("unroll")                                                      \
        for (int p = 0; p < 4; ++p) {                                          \
            int byte = (srow + p * 32) * 128 + (sswz << 4);                    \
            int4 wa, wb;                                                       \
            wa.x = pk_bf16(ra[p][0].x, ra[p][0].y);                            \
            wa.y = pk_bf16(ra[p][0].z, ra[p][0].w);                            \
            wa.z = pk_bf16(ra[p][1].x, ra[p][1].y);                            \
            wa.w = pk_bf16(ra[p][1].z, ra[p][1].w);                            \
            wb.x = pk_bf16(rb[p][0].x, rb[p][0].y);                            \
            wb.y = pk_bf16(rb[p][0].z, rb[p][0].w);                            \
            wb.z = pk_bf16(rb[p][1].x, rb[p][1].y);                            \
            wb.w = pk_bf16(rb[p][1].z, rb[p][1].w);                            \
            *(int4*)&lds[buf][0][byte] = wa;                                   \
            *(int4*)&lds[buf][1][byte] = wb;                                   \
        }

    f32x4 acc[4][4] = {};
    const int fr = lane & 15, fq = lane >> 4;
    int arow[4], brow[4];
    #pragma unroll
    for (int f = 0; f < 4; ++f) { arow[f] = wm*64+f*16+fr; brow[f] = wn*64+f*16+fr; }

    LOADT(0); WRITET(0); __syncthreads();
    for (int kt = 0; kt < 4; ++kt) {
        if (kt + 1 < 4) { LOADT(kt + 1); }
        const int buf = kt & 1;
        #pragma unroll
        for (int kk = 0; kk < 2; ++kk) {
            bf16x8 af[4], bf[4];
            #pragma unroll
            for (int f = 0; f < 4; ++f) {
                int sa = (fq + kk * 4) ^ (arow[f] & 7);
                int sb = (fq + kk * 4) ^ (brow[f] & 7);
                af[f] = *(const bf16x8*)&lds[buf][0][arow[f] * 128 + (sa << 4)];
                bf[f] = *(const bf16x8*)&lds[buf][1][brow[f] * 128 + (sb << 4)];
            }
            #pragma unroll
            for (int mf = 0; mf < 4; ++mf)
                #pragma unroll
                for (int nf = 0; nf < 4; ++nf)
                    acc[mf][nf] = __builtin_amdgcn_mfma_f32_16x16x32_bf16(
                        af[mf], bf[nf], acc[mf][nf], 0, 0, 0);
        }
        if (kt + 1 < 4) { __syncthreads(); WRITET(buf ^ 1); __syncthreads(); }
    }

    float xq[4][4];
    #pragma unroll
    for (int mf = 0; mf < 4; ++mf)
        #pragma unroll
        for (int r = 0; r < 4; ++r)
            xq[mf][r] = xq2[qb + wm * 64 + mf * 16 + fq * 4 + r];
    float nv[4][4] = {}, dv[4][4] = {};
    #pragma unroll
    for (int nf = 0; nf < 4; ++nf) {
        int n = tb + wn * 64 + nf * 16 + fr;
        float t2 = xt2[n], yvv = y[n];
        #pragma unroll
        for (int mf = 0; mf < 4; ++mf)
            #pragma unroll
            for (int r = 0; r < 4; ++r) {
                float d2 = xq[mf][r] + t2 - 2.0f * acc[mf][nf][r];
                float w  = __expf(-12.5f * d2);
                nv[mf][r] += w * yvv; dv[mf][r] += w;
            }
    }
    #pragma unroll
    for (int off = 1; off < 16; off <<= 1)
        #pragma unroll
        for (int mf = 0; mf < 4; ++mf)
            #pragma unroll
            for (int r = 0; r < 4; ++r) {
                nv[mf][r] += __shfl_xor(nv[mf][r], off);
                dv[mf][r] += __shfl_xor(dv[mf][r], off);
            }
    if (fr == 0) {
        #pragma unroll
        for (int mf = 0; mf < 4; ++mf)
            #pragma unroll
            for (int r = 0; r < 4; ++r) {
                int m = qb + wm * 64 + mf * 16 + fq * 4 + r;
                atomicAdd(&num[m], nv[mf][r]);
                atomicAdd(&den[m], dv[mf][r]);
            }
    }
    #undef LOADT
    #undef WRITET
}

__global__ void grnn_final(const float* __restrict__ num,
                           const float* __restrict__ den,
                           float* __restrict__ out) {
    int i = blockIdx.x * 256 + threadIdx.x;
    if (i < N_Q) out[i] = num[i] / (den[i] + 1e-9f);
}

// ---- launch -----------------------------------------------------------------
extern "C" void kernel_launch(void* const* d_in, const int* in_sizes, int n_in,
                              void* d_out, int out_size, void* d_ws, size_t ws_size,
                              hipStream_t stream) {
    const float* X  = (const float*)d_in[0];
    const float* XT = (const float*)d_in[1];
    const float* y  = (const float*)d_in[2];
    float* out = (float*)d_out;
    char*  ws  = (char*)d_ws;

    const size_t off_pnum = 0;                                  // 512 KB
    const size_t off_pden = off_pnum + (size_t)N_Q * NC * 4;    // 512 KB
    const size_t off_xt2  = off_pden + (size_t)N_Q * NC * 4;    // 32 KB
    const size_t off_Xb   = off_xt2  + (size_t)N_T * 4;         // 1 MB fp8
    const size_t off_XTb  = off_Xb   + (size_t)N_Q * DIM;       // 2 MB fp8
    const size_t need     = off_XTb  + (size_t)N_T * DIM;       // ~4.03 MB

    if (ws_size >= need) {
        float* pnum = (float*)(ws + off_pnum);
        float* pden = (float*)(ws + off_pden);
        float* xt2s = (float*)(ws + off_xt2);
        unsigned char* Xb  = (unsigned char*)(ws + off_Xb);
        unsigned char* XTb = (unsigned char*)(ws + off_XTb);
        hipLaunchKernelGGL(grnn_prep, dim3((N_Q + N_T) / 16), dim3(256), 0, stream,
                           X, XT, xt2s, Xb, XTb);
        hipLaunchKernelGGL(grnn_mfma8, dim3(NXB * NYB), dim3(512), 0, stream,
                           Xb, XTb, y, xt2s, pnum, pden);
        hipLaunchKernelGGL(grnn_reduce, dim3(N_Q / 8), dim3(256), 0, stream,
                           pnum, pden, out);
    } else {
        float* num = (float*)ws;
        float* den = num + N_Q;
        float* xq2 = num + 2 * N_Q;
        float* xt2 = num + 3 * N_Q;
        hipLaunchKernelGGL(grnn_zero, dim3((2 * N_Q + 255) / 256), dim3(256), 0, stream,
                           (float*)ws);
        hipLaunchKernelGGL(grnn_rowsq, dim3((N_Q + N_T + 3) / 4), dim3(256), 0, stream,
                           X, XT, xq2, xt2);
        hipLaunchKernelGGL(grnn_mfma_atomic, dim3(N_T / 128, N_Q / 128), dim3(256), 0, stream,
                           X, XT, y, xq2, xt2, num, den);
        hipLaunchKernelGGL(grnn_final, dim3((N_Q + 255) / 256), dim3(256), 0, stream,
                           num, den, out);
    }
}